// Round 14
// baseline (1443.147 us; speedup 1.0000x reference)
//
#include <hip/hip_runtime.h>

#define T_SEQ  1024
#define NBATCH 512
#define IN_DIM 16
#define HDIM   128
#define G4     (4 * HDIM)
#define TC     64
#define NCHUNK (T_SEQ / TC)
#define NWGH   256   // WGs per role; 2 batches per WG

typedef unsigned short ushort_t;
typedef __attribute__((ext_vector_type(8))) _Float16 f16x8;
typedef __attribute__((ext_vector_type(4))) float f32x4;

#define MFMA16(a, b, c) __builtin_amdgcn_mfma_f32_16x16x32_f16((a), (b), (c), 0, 0, 0)

__device__ __forceinline__ float sigf(float x) {
  return __builtin_amdgcn_rcpf(1.0f + __expf(-x));
}
__device__ __forceinline__ float tanhf_fast(float x) {
  return 1.0f - 2.0f * __builtin_amdgcn_rcpf(1.0f + __expf(2.0f * x));
}
__device__ __forceinline__ ushort_t f16_bits(float f) {
  const _Float16 h = (_Float16)f;
  return __builtin_bit_cast(unsigned short, h);
}
__device__ __forceinline__ void split_f16(float f, ushort_t* hi, ushort_t* lo) {
  const _Float16 h = (_Float16)f;
  *hi = __builtin_bit_cast(unsigned short, h);
  const _Float16 l = (_Float16)(f - (float)h);
  *lo = __builtin_bit_cast(unsigned short, l);
}
// barrier that waits only on LDS ops (global stores stay in flight)
__device__ __forceinline__ void bar_lds() {
  asm volatile("s_waitcnt lgkmcnt(0)\n\ts_barrier" ::: "memory");
}

// ---------------- prep: split weights into fp16 hi/lo ----------------
__global__ __launch_bounds__(256) void prep_weights(
    const float* __restrict__ Whh0, const float* __restrict__ Whh1,
    const float* __restrict__ Wih0, const float* __restrict__ Wih1,
    ushort_t* __restrict__ w0h, ushort_t* __restrict__ w0l,
    ushort_t* __restrict__ w1h, ushort_t* __restrict__ w1l,
    ushort_t* __restrict__ wxh, ushort_t* __restrict__ wxl,
    ushort_t* __restrict__ wi1h, ushort_t* __restrict__ wi1l)
{
  const int idx = blockIdx.x * 256 + threadIdx.x;
  if (idx < 512 * HDIM) {
    split_f16(Whh0[idx], &w0h[idx], &w0l[idx]);
    split_f16(Whh1[idx], &w1h[idx], &w1l[idx]);
    split_f16(Wih1[idx], &wi1h[idx], &wi1l[idx]);
  }
  if (idx < 512 * 32) {  // Wih0 zero-padded K=16 -> 32
    const int g = idx >> 5, k = idx & 31;
    const float f = (k < IN_DIM) ? Wih0[g * IN_DIM + k] : 0.0f;
    split_f16(f, &wxh[idx], &wxl[idx]);
  }
}

// LDS overlay: both roles share one pool so per-WG LDS is small enough for
// 2 co-resident WGs per CU (2 independent barrier groups -> latency hiding).
struct L0LDS {
  __align__(16) ushort_t hfA[2][144];
  __align__(16) ushort_t hfB[2][144];
  __align__(16) ushort_t xlds[2][TC][32];
};
struct L1LDS {
  __align__(16) ushort_t hfA[2][144];
  __align__(16) ushort_t hfB[2][144];
  __align__(16) ushort_t h2l[TC][2][136];
  __align__(16) float wfl[HDIM];
};

// ---------------- pipelined launch: l0(ch) on WGs [0,256), gemm+l1(ch-1) on
// WGs [256,512). 2 batches per WG; A rows carry batch = row>>3; C rows give
// every lane (kq, col j) the full (i,f,g,o) for (batch kq>>1, hidden j):
// lane-pairs duplicate the update with identical values (benign). Recurrent
// h.Whh uses the fp16 HI term only (W_lo dropped: adds ~4e-5 rms/gate, under
// the fp16-h quantization noise already present); x-path and gx1 GEMM keep
// hi+lo. Chain split: h-MFMA chain (4) || x-MFMA chain (2), summed at the end.
__global__ __launch_bounds__(512, 2) void lstm_pipe(
    const float* __restrict__ x,
    const ushort_t* __restrict__ w0h,
    const ushort_t* __restrict__ wxh, const ushort_t* __restrict__ wxl,
    const float* __restrict__ bih0, const float* __restrict__ bhh0,
    const ushort_t* __restrict__ wi1h, const ushort_t* __restrict__ wi1l,
    const ushort_t* __restrict__ w1h,
    const float* __restrict__ bih1, const float* __restrict__ bhh1,
    const float* __restrict__ Wfc, const float* __restrict__ bfc,
    float* __restrict__ out,
    float* __restrict__ h1s, float* __restrict__ c1s,
    float* __restrict__ h2s, float* __restrict__ c2s,
    ushort_t* __restrict__ h1buf,   // [2][NWGH][TC*2][HDIM] fp16
    float* __restrict__ gx1buf,     // [NWGH][TC*2][HDIM][4]
    int ch)
{
  const int tid  = threadIdx.x;
  const int lane = tid & 63;
  const int wv   = tid >> 6;
  const int row  = lane & 15;
  const int kq   = lane >> 4;
  const int uq   = kq >> 1;      // this lane's batch in the update phase
  const int bq   = row >> 3;     // A-fragment batch for this lane's A row
  const int j    = wv * 16 + row;

  __shared__ __align__(16) char pool[sizeof(L1LDS)];

  if (blockIdx.x < NWGH) {
    // ================= L0 ROLE: chunk ch =================
    if (ch >= NCHUNK) return;
    L0LDS& S = *(L0LDS*)pool;
    const int w  = blockIdx.x;
    const int b0 = w * 2;

    f16x8 Bh[4][4], Bxh[4], Bxl[4];
#pragma unroll
    for (int i = 0; i < 4; ++i) {
      const int g = i * 128 + j;
#pragma unroll
      for (int kt = 0; kt < 4; ++kt)
        Bh[i][kt] = *(const f16x8*)&w0h[g * HDIM + kt * 32 + kq * 8];
      Bxh[i] = *(const f16x8*)&wxh[g * 32 + kq * 8];
      Bxl[i] = *(const f16x8*)&wxl[g * 32 + kq * 8];
    }

    // stage this chunk's x as fp16: 256 tasks = 2 batches x TC steps x 2 halves
    if (tid < 256) {
      const int half = tid & 1;
      const int ts   = (tid >> 1) & (TC - 1);
      const int b    = tid >> 7;
      const float* src =
          &x[((size_t)(b0 + b) * T_SEQ + ch * TC + ts) * IN_DIM + half * 8];
      const float4 v0 = *(const float4*)&src[0];
      const float4 v1 = *(const float4*)&src[4];
      ushort_t* dst = &S.xlds[b][ts][half * 8];
      dst[0] = f16_bits(v0.x); dst[1] = f16_bits(v0.y);
      dst[2] = f16_bits(v0.z); dst[3] = f16_bits(v0.w);
      dst[4] = f16_bits(v1.x); dst[5] = f16_bits(v1.y);
      dst[6] = f16_bits(v1.z); dst[7] = f16_bits(v1.w);
      *(float4*)&S.xlds[b][ts][16 + half * 8] = (float4){0.f, 0.f, 0.f, 0.f};
    }

    float bz[4];
#pragma unroll
    for (int i = 0; i < 4; ++i) bz[i] = bih0[i * 128 + j] + bhh0[i * 128 + j];
    float hc = h1s[(size_t)(b0 + uq) * HDIM + j];
    float cc = c1s[(size_t)(b0 + uq) * HDIM + j];
    S.hfA[uq][j] = f16_bits(hc);
    __syncthreads();

    ushort_t* hbp = h1buf + ((size_t)(ch & 1) * NWGH + w) * (TC * 2 * HDIM) +
                    (size_t)uq * HDIM + j;

#define L0_STEP(HIN, HOUT, TT)                                              \
  {                                                                         \
    const f16x8 ax = *(const f16x8*)&S.xlds[bq][TT][kq * 8];                \
    f32x4 aH[4], aX[4];                                                     \
    _Pragma("unroll") for (int i = 0; i < 4; ++i) {                         \
      aH[i] = (f32x4){0.f, 0.f, 0.f, 0.f};                                  \
      aX[i] = (f32x4){0.f, 0.f, 0.f, 0.f};                                  \
    }                                                                       \
    _Pragma("unroll") for (int kt = 0; kt < 4; ++kt) {                      \
      const f16x8 ah = *(const f16x8*)&S.HIN[bq][kt * 32 + kq * 8];         \
      _Pragma("unroll") for (int i = 0; i < 4; ++i)                         \
          aH[i] = MFMA16(ah, Bh[i][kt], aH[i]);                             \
    }                                                                       \
    _Pragma("unroll") for (int i = 0; i < 4; ++i)                           \
        aX[i] = MFMA16(ax, Bxh[i], aX[i]);                                  \
    _Pragma("unroll") for (int i = 0; i < 4; ++i)                           \
        aX[i] = MFMA16(ax, Bxl[i], aX[i]);                                  \
    const float ig = sigf(aH[0][0] + aX[0][0] + bz[0]);                     \
    const float fg = sigf(aH[1][0] + aX[1][0] + bz[1]);                     \
    const float gg = tanhf_fast(aH[2][0] + aX[2][0] + bz[2]);               \
    const float og = sigf(aH[3][0] + aX[3][0] + bz[3]);                     \
    cc = fg * cc + ig * gg;                                                 \
    hc = og * tanhf_fast(cc);                                               \
    const ushort_t hbits = f16_bits(hc);                                    \
    S.HOUT[uq][j] = hbits;                                                  \
    *hbp = hbits;                                                           \
    hbp += 2 * HDIM;                                                        \
    bar_lds();                                                              \
  }

    for (int tt = 0; tt < TC; tt += 2) {
      L0_STEP(hfA, hfB, tt);
      L0_STEP(hfB, hfA, tt + 1);
    }
#undef L0_STEP

    h1s[(size_t)(b0 + uq) * HDIM + j] = hc;
    c1s[(size_t)(b0 + uq) * HDIM + j] = cc;
  } else {
    // ================= L1 ROLE: gemm + recurrence, FC at chunk end =========
    if (ch == 0) return;
    L1LDS& S = *(L1LDS*)pool;
    const int w  = blockIdx.x - NWGH;
    const int b0 = w * 2;

    const ushort_t* hb =
        h1buf + ((size_t)((ch - 1) & 1) * NWGH + w) * (TC * 2 * HDIM);
    float* gx = gx1buf + (size_t)w * (TC * 2 * HDIM * 4);

    if (tid < HDIM) S.wfl[tid] = Wfc[tid];

    // ---- gemm: gx1 = h1 . Wih1^T + biases (hi+lo), own 2 batches ----
    {
      f16x8 Gh[4][4], Gl[4][4];
      float bz1[4];
#pragma unroll
      for (int i = 0; i < 4; ++i) {
        const int g = i * 128 + j;
#pragma unroll
        for (int kt = 0; kt < 4; ++kt) {
          const int off = g * HDIM + kt * 32 + kq * 8;
          Gh[i][kt] = *(const f16x8*)&wi1h[off];
          Gl[i][kt] = *(const f16x8*)&wi1l[off];
        }
        bz1[i] = bih1[i * 128 + j] + bhh1[i * 128 + j];
      }
#pragma unroll 2
      for (int mt = 0; mt < TC * 2 / 16; ++mt) {
        f32x4 acc[4];
#pragma unroll
        for (int i = 0; i < 4; ++i) acc[i] = (f32x4){0.f, 0.f, 0.f, 0.f};
#pragma unroll
        for (int kt = 0; kt < 4; ++kt) {
          const f16x8 a =
              *(const f16x8*)&hb[(size_t)(mt * 16 + row) * HDIM + kt * 32 + kq * 8];
#pragma unroll
          for (int i = 0; i < 4; ++i) acc[i] = MFMA16(a, Gh[i][kt], acc[i]);
#pragma unroll
          for (int i = 0; i < 4; ++i) acc[i] = MFMA16(a, Gl[i][kt], acc[i]);
        }
#pragma unroll
        for (int r = 0; r < 4; ++r) {
          const int m = mt * 16 + kq * 4 + r;
          float4 o;
          o.x = acc[0][r] + bz1[0];
          o.y = acc[1][r] + bz1[1];
          o.z = acc[2][r] + bz1[2];
          o.w = acc[3][r] + bz1[3];
          *(float4*)&gx[((size_t)m * HDIM + j) * 4] = o;
        }
      }
    }

    float hc = h2s[(size_t)(b0 + uq) * HDIM + j];
    float cc = c2s[(size_t)(b0 + uq) * HDIM + j];
    S.hfA[uq][j] = f16_bits(hc);
    __syncthreads();  // drains gemm stores (vmcnt) + hfA/wfl staging

    f16x8 Rh[4][4];
#pragma unroll
    for (int i = 0; i < 4; ++i) {
      const int g = i * 128 + j;
#pragma unroll
      for (int kt = 0; kt < 4; ++kt)
        Rh[i][kt] = *(const f16x8*)&w1h[g * HDIM + kt * 32 + kq * 8];
    }

    // per-step stride: 2 rows x HDIM x 4 floats = 1024 floats = 256 float4
    const float4* gxp = (const float4*)gx + ((size_t)uq * HDIM + j);
    float4 zcc = *gxp;
    gxp += 256;

#define L1_STEP(HIN, HOUT, TT)                                              \
  {                                                                         \
    const float4 zcu = zcc;                                                 \
    if ((TT) + 1 < TC) { zcc = *gxp; gxp += 256; }                          \
    f32x4 aH[4];                                                            \
    _Pragma("unroll") for (int i = 0; i < 4; ++i)                           \
        aH[i] = (f32x4){0.f, 0.f, 0.f, 0.f};                                \
    _Pragma("unroll") for (int kt = 0; kt < 4; ++kt) {                      \
      const f16x8 ah = *(const f16x8*)&S.HIN[bq][kt * 32 + kq * 8];         \
      _Pragma("unroll") for (int i = 0; i < 4; ++i)                         \
          aH[i] = MFMA16(ah, Rh[i][kt], aH[i]);                             \
    }                                                                       \
    const float ig = sigf(aH[0][0] + zcu.x);                                \
    const float fg = sigf(aH[1][0] + zcu.y);                                \
    const float gg = tanhf_fast(aH[2][0] + zcu.z);                          \
    const float og = sigf(aH[3][0] + zcu.w);                                \
    cc = fg * cc + ig * gg;                                                 \
    hc = og * tanhf_fast(cc);                                               \
    const ushort_t hbits = f16_bits(hc);                                    \
    S.HOUT[uq][j] = hbits;                                                  \
    S.h2l[TT][uq][j] = hbits;                                               \
    bar_lds();                                                              \
  }

    for (int tt = 0; tt < TC; tt += 2) {
      L1_STEP(hfA, hfB, tt);
      L1_STEP(hfB, hfA, tt + 1);
    }
#undef L1_STEP

    h2s[(size_t)(b0 + uq) * HDIM + j] = hc;
    c2s[(size_t)(b0 + uq) * HDIM + j] = cc;

    // ---- FC pass over the chunk (latency-tolerant, once per chunk) ----
    // last bar_lds made all h2l writes visible
    if (tid < TC * 2) {
      const int tt = tid >> 1, b = tid & 1;
      const float bfcv = bfc[0];
      float s0 = 0.f, s1 = 0.f, s2 = 0.f, s3 = 0.f;
#pragma unroll
      for (int q = 0; q < HDIM / 8; ++q) {
        const f16x8 hv = *(const f16x8*)&S.h2l[tt][b][q * 8];
        const float* wq = &S.wfl[q * 8];
        s0 += fmaxf((float)hv[0], 0.f) * wq[0];
        s1 += fmaxf((float)hv[1], 0.f) * wq[1];
        s2 += fmaxf((float)hv[2], 0.f) * wq[2];
        s3 += fmaxf((float)hv[3], 0.f) * wq[3];
        s0 += fmaxf((float)hv[4], 0.f) * wq[4];
        s1 += fmaxf((float)hv[5], 0.f) * wq[5];
        s2 += fmaxf((float)hv[6], 0.f) * wq[6];
        s3 += fmaxf((float)hv[7], 0.f) * wq[7];
      }
      const float s = s0 + s1 + s2 + s3 + bfcv;
      out[(size_t)(b0 + b) * T_SEQ + (ch - 1) * TC + tt] = fmaxf(s, 0.0f);
    }
  }
}

extern "C" void kernel_launch(void* const* d_in, const int* in_sizes, int n_in,
                              void* d_out, int out_size, void* d_ws, size_t ws_size,
                              hipStream_t stream)
{
  const float* x    = (const float*)d_in[0];
  const float* Wih0 = (const float*)d_in[1];
  const float* Whh0 = (const float*)d_in[2];
  const float* bih0 = (const float*)d_in[3];
  const float* bhh0 = (const float*)d_in[4];
  const float* Wih1 = (const float*)d_in[5];
  const float* Whh1 = (const float*)d_in[6];
  const float* bih1 = (const float*)d_in[7];
  const float* bhh1 = (const float*)d_in[8];
  const float* Wfc  = (const float*)d_in[9];
  const float* bfc  = (const float*)d_in[10];
  float* out = (float*)d_out;

  const size_t stateN = (size_t)NBATCH * HDIM;  // 65536
  float* h1s = (float*)d_ws;
  float* c1s = h1s + stateN;
  float* h2s = c1s + stateN;
  float* c2s = h2s + stateN;
  ushort_t* w0h  = (ushort_t*)(c2s + stateN);
  ushort_t* w0l  = w0h  + stateN;
  ushort_t* w1h  = w0l  + stateN;
  ushort_t* w1l  = w1h  + stateN;
  ushort_t* wi1h = w1l  + stateN;
  ushort_t* wi1l = wi1h + stateN;
  ushort_t* wxh  = wi1l + stateN;
  ushort_t* wxl  = wxh  + 512 * 32;
  ushort_t* h1buf = wxl + 512 * 32;            // 2*NWGH*TC*2*HDIM fp16 = 16.8MB
  float* gx1buf = (float*)(h1buf + (size_t)2 * NWGH * TC * 2 * HDIM);  // 67MB

  // zero-init recurrent states (h0 = c0 = 0)
  (void)hipMemsetAsync(d_ws, 0, 4 * stateN * sizeof(float), stream);
  hipLaunchKernelGGL(prep_weights, dim3(256), dim3(256), 0, stream,
                     Whh0, Whh1, Wih0, Wih1,
                     w0h, w0l, w1h, w1l, wxh, wxl, wi1h, wi1l);

  for (int ch = 0; ch <= NCHUNK; ++ch) {
    hipLaunchKernelGGL(lstm_pipe, dim3(2 * NWGH), dim3(512), 0, stream,
                       x, w0h, wxh, wxl, bih0, bhh0,
                       wi1h, wi1l, w1h, bih1, bhh1, Wfc, bfc,
                       out, h1s, c1s, h2s, c2s, h1buf, gx1buf, ch);
  }
}

// Round 15
// 991.071 us; speedup vs baseline: 1.4561x; 1.4561x over previous
//
#include <hip/hip_runtime.h>

#define T_SEQ  1024
#define NBATCH 512
#define IN_DIM 16
#define HDIM   128
#define G4     (4 * HDIM)
#define TC     64
#define NCHUNK (T_SEQ / TC)
#define NWGH   128   // WGs per role; 4 batches per WG

typedef unsigned short ushort_t;
typedef __attribute__((ext_vector_type(8))) _Float16 f16x8;
typedef __attribute__((ext_vector_type(4))) float f32x4;

#define MFMA16(a, b, c) __builtin_amdgcn_mfma_f32_16x16x32_f16((a), (b), (c), 0, 0, 0)

__device__ __forceinline__ float sigf(float x) {
  return __builtin_amdgcn_rcpf(1.0f + __expf(-x));
}
__device__ __forceinline__ float tanhf_fast(float x) {
  return 1.0f - 2.0f * __builtin_amdgcn_rcpf(1.0f + __expf(2.0f * x));
}
__device__ __forceinline__ ushort_t f16_bits(float f) {
  const _Float16 h = (_Float16)f;
  return __builtin_bit_cast(unsigned short, h);
}
__device__ __forceinline__ void split_f16(float f, ushort_t* hi, ushort_t* lo) {
  const _Float16 h = (_Float16)f;
  *hi = __builtin_bit_cast(unsigned short, h);
  const _Float16 l = (_Float16)(f - (float)h);
  *lo = __builtin_bit_cast(unsigned short, l);
}
// barrier that waits only on LDS ops (global stores stay in flight)
__device__ __forceinline__ void bar_lds() {
  asm volatile("s_waitcnt lgkmcnt(0)\n\ts_barrier" ::: "memory");
}

// ---------------- prep: split weights into fp16 hi/lo ----------------
__global__ __launch_bounds__(256) void prep_weights(
    const float* __restrict__ Whh0, const float* __restrict__ Whh1,
    const float* __restrict__ Wih0, const float* __restrict__ Wih1,
    ushort_t* __restrict__ w0h, ushort_t* __restrict__ w0l,
    ushort_t* __restrict__ w1h, ushort_t* __restrict__ w1l,
    ushort_t* __restrict__ wxh, ushort_t* __restrict__ wxl,
    ushort_t* __restrict__ wi1h, ushort_t* __restrict__ wi1l)
{
  const int idx = blockIdx.x * 256 + threadIdx.x;
  if (idx < 512 * HDIM) {
    split_f16(Whh0[idx], &w0h[idx], &w0l[idx]);
    split_f16(Whh1[idx], &w1h[idx], &w1l[idx]);
    split_f16(Wih1[idx], &wi1h[idx], &wi1l[idx]);
  }
  if (idx < 512 * 32) {  // Wih0 zero-padded K=16 -> 32
    const int g = idx >> 5, k = idx & 31;
    const float f = (k < IN_DIM) ? Wih0[g * IN_DIM + k] : 0.0f;
    split_f16(f, &wxh[idx], &wxl[idx]);
  }
}

// ---------------- pipelined launch: l0(ch) on WGs [0,128), gemm+l1(ch-1) on
// WGs [128,256). Coherence of the h1buf handoff comes from the kernel boundary
// between launches. Gate cols permuted (g = i*128 + wv*16 + row); A rows carry
// batch = row>>2, so every lane (kq, col j) owns (i,f,g,o) for (batch kq,
// hidden j) -> in-lane update on all 64 lanes. Recurrent h.Whh uses the fp16
// HI term only (W_lo dropped — validated in R14: absmax unchanged at 1.2e-4);
// x-path and gx1 GEMM keep hi+lo. L0 chains: h (depth 4) || x (depth 2).
__global__ __launch_bounds__(512, 2) void lstm_pipe(
    const float* __restrict__ x,
    const ushort_t* __restrict__ w0h,
    const ushort_t* __restrict__ wxh, const ushort_t* __restrict__ wxl,
    const float* __restrict__ bih0, const float* __restrict__ bhh0,
    const ushort_t* __restrict__ wi1h, const ushort_t* __restrict__ wi1l,
    const ushort_t* __restrict__ w1h,
    const float* __restrict__ bih1, const float* __restrict__ bhh1,
    const float* __restrict__ Wfc, const float* __restrict__ bfc,
    float* __restrict__ out,
    float* __restrict__ h1s, float* __restrict__ c1s,
    float* __restrict__ h2s, float* __restrict__ c2s,
    ushort_t* __restrict__ h1buf,   // [2][NWGH][TC*4][HDIM] fp16
    float* __restrict__ gx1buf,     // [NWGH][TC*4][HDIM][4]
    int ch)
{
  const int tid  = threadIdx.x;
  const int lane = tid & 63;
  const int wv   = tid >> 6;
  const int row  = lane & 15;
  const int kq   = lane >> 4;    // = this lane's batch in the update phase
  const int bq   = row >> 2;     // A-fragment batch for this lane's A row
  const int j    = wv * 16 + row;

  if (blockIdx.x < NWGH) {
    // ================= L0 ROLE: chunk ch =================
    if (ch >= NCHUNK) return;
    const int w  = blockIdx.x;
    const int b0 = w * 4;

    __shared__ __align__(16) ushort_t hfA[4][144], hfB[4][144];
    __shared__ __align__(16) ushort_t xlds[4][TC][32];

    f16x8 Bh[4][4], Bxh[4], Bxl[4];
#pragma unroll
    for (int i = 0; i < 4; ++i) {
      const int g = i * 128 + j;
#pragma unroll
      for (int kt = 0; kt < 4; ++kt)
        Bh[i][kt] = *(const f16x8*)&w0h[g * HDIM + kt * 32 + kq * 8];
      Bxh[i] = *(const f16x8*)&wxh[g * 32 + kq * 8];
      Bxl[i] = *(const f16x8*)&wxl[g * 32 + kq * 8];
    }

    // stage this chunk's x as fp16 (2 threads per (b,ts) row)
    {
      const int r = tid >> 1, half = tid & 1;
      const int b = r >> 6, ts = r & (TC - 1);
      const float* src =
          &x[((size_t)(b0 + b) * T_SEQ + ch * TC + ts) * IN_DIM + half * 8];
      const float4 v0 = *(const float4*)&src[0];
      const float4 v1 = *(const float4*)&src[4];
      ushort_t* dst = &xlds[b][ts][half * 8];
      dst[0] = f16_bits(v0.x); dst[1] = f16_bits(v0.y);
      dst[2] = f16_bits(v0.z); dst[3] = f16_bits(v0.w);
      dst[4] = f16_bits(v1.x); dst[5] = f16_bits(v1.y);
      dst[6] = f16_bits(v1.z); dst[7] = f16_bits(v1.w);
      *(float4*)&xlds[b][ts][16 + half * 8] = (float4){0.f, 0.f, 0.f, 0.f};
    }

    float bz[4];
#pragma unroll
    for (int i = 0; i < 4; ++i) bz[i] = bih0[i * 128 + j] + bhh0[i * 128 + j];
    float hc = h1s[(size_t)(b0 + kq) * HDIM + j];
    float cc = c1s[(size_t)(b0 + kq) * HDIM + j];
    hfA[kq][j] = f16_bits(hc);
    __syncthreads();

    ushort_t* hbp = h1buf + ((size_t)(ch & 1) * NWGH + w) * (TC * 4 * HDIM) +
                    (size_t)kq * HDIM + j;

#define L0_STEP(HIN, HOUT, TT)                                              \
  {                                                                         \
    const f16x8 ax = *(const f16x8*)&xlds[bq][TT][kq * 8];                  \
    f32x4 aH[4], aX[4];                                                     \
    _Pragma("unroll") for (int i = 0; i < 4; ++i) {                         \
      aH[i] = (f32x4){0.f, 0.f, 0.f, 0.f};                                  \
      aX[i] = (f32x4){0.f, 0.f, 0.f, 0.f};                                  \
    }                                                                       \
    _Pragma("unroll") for (int kt = 0; kt < 4; ++kt) {                      \
      const f16x8 ah = *(const f16x8*)&HIN[bq][kt * 32 + kq * 8];           \
      _Pragma("unroll") for (int i = 0; i < 4; ++i)                         \
          aH[i] = MFMA16(ah, Bh[i][kt], aH[i]);                             \
    }                                                                       \
    _Pragma("unroll") for (int i = 0; i < 4; ++i)                           \
        aX[i] = MFMA16(ax, Bxh[i], aX[i]);                                  \
    _Pragma("unroll") for (int i = 0; i < 4; ++i)                           \
        aX[i] = MFMA16(ax, Bxl[i], aX[i]);                                  \
    const float ig = sigf(aH[0][0] + aX[0][0] + bz[0]);                     \
    const float fg = sigf(aH[1][0] + aX[1][0] + bz[1]);                     \
    const float gg = tanhf_fast(aH[2][0] + aX[2][0] + bz[2]);               \
    const float og = sigf(aH[3][0] + aX[3][0] + bz[3]);                     \
    cc = fg * cc + ig * gg;                                                 \
    hc = og * tanhf_fast(cc);                                               \
    const ushort_t hbits = f16_bits(hc);                                    \
    HOUT[kq][j] = hbits;                                                    \
    *hbp = hbits;                                                           \
    hbp += 4 * HDIM;                                                        \
    bar_lds();                                                              \
  }

    for (int tt = 0; tt < TC; tt += 2) {
      L0_STEP(hfA, hfB, tt);
      L0_STEP(hfB, hfA, tt + 1);
    }
#undef L0_STEP

    h1s[(size_t)(b0 + kq) * HDIM + j] = hc;
    c1s[(size_t)(b0 + kq) * HDIM + j] = cc;
  } else {
    // ================= L1 ROLE: gemm + recurrence, FC at chunk end =========
    if (ch == 0) return;
    const int w  = blockIdx.x - NWGH;
    const int b0 = w * 4;

    __shared__ __align__(16) ushort_t hf1A[4][144], hf1B[4][144];
    __shared__ __align__(16) ushort_t h2l[TC][4][136];  // fp16 h2 for FC pass
    __shared__ float wfl[HDIM];

    const ushort_t* hb =
        h1buf + ((size_t)((ch - 1) & 1) * NWGH + w) * (TC * 4 * HDIM);
    float* gx = gx1buf + (size_t)w * (TC * 4 * HDIM * 4);

    if (tid < HDIM) wfl[tid] = Wfc[tid];

    // ---- gemm: gx1 = h1 . Wih1^T + biases (hi+lo), own 4 batches only ----
    {
      f16x8 Gh[4][4], Gl[4][4];
      float bz1[4];
#pragma unroll
      for (int i = 0; i < 4; ++i) {
        const int g = i * 128 + j;
#pragma unroll
        for (int kt = 0; kt < 4; ++kt) {
          const int off = g * HDIM + kt * 32 + kq * 8;
          Gh[i][kt] = *(const f16x8*)&wi1h[off];
          Gl[i][kt] = *(const f16x8*)&wi1l[off];
        }
        bz1[i] = bih1[i * 128 + j] + bhh1[i * 128 + j];
      }
#pragma unroll 2
      for (int mt = 0; mt < TC * 4 / 16; ++mt) {
        f32x4 acc[4];
#pragma unroll
        for (int i = 0; i < 4; ++i) acc[i] = (f32x4){0.f, 0.f, 0.f, 0.f};
#pragma unroll
        for (int kt = 0; kt < 4; ++kt) {
          const f16x8 a =
              *(const f16x8*)&hb[(size_t)(mt * 16 + row) * HDIM + kt * 32 + kq * 8];
#pragma unroll
          for (int i = 0; i < 4; ++i) acc[i] = MFMA16(a, Gh[i][kt], acc[i]);
#pragma unroll
          for (int i = 0; i < 4; ++i) acc[i] = MFMA16(a, Gl[i][kt], acc[i]);
        }
#pragma unroll
        for (int r = 0; r < 4; ++r) {
          const int m = mt * 16 + kq * 4 + r;
          float4 o;
          o.x = acc[0][r] + bz1[0];
          o.y = acc[1][r] + bz1[1];
          o.z = acc[2][r] + bz1[2];
          o.w = acc[3][r] + bz1[3];
          *(float4*)&gx[((size_t)m * HDIM + j) * 4] = o;
        }
      }
    }

    float hc = h2s[(size_t)(b0 + kq) * HDIM + j];
    float cc = c2s[(size_t)(b0 + kq) * HDIM + j];
    hf1A[kq][j] = f16_bits(hc);
    __syncthreads();  // drains gemm stores (vmcnt) + hf1A/wfl staging

    f16x8 Rh[4][4];
#pragma unroll
    for (int i = 0; i < 4; ++i) {
      const int g = i * 128 + j;
#pragma unroll
      for (int kt = 0; kt < 4; ++kt)
        Rh[i][kt] = *(const f16x8*)&w1h[g * HDIM + kt * 32 + kq * 8];
    }

    // per-step stride: 4 rows x HDIM x 4 floats = 2048 floats = 512 float4
    const float4* gxp = (const float4*)&gx[((size_t)kq * HDIM + j) * 4];
    float4 zcc = *gxp;
    gxp += 512;

#define L1_STEP(HIN, HOUT, TT)                                              \
  {                                                                         \
    const float4 zcu = zcc;                                                 \
    if ((TT) + 1 < TC) { zcc = *gxp; gxp += 512; }                          \
    f32x4 aH[4];                                                            \
    _Pragma("unroll") for (int i = 0; i < 4; ++i)                           \
        aH[i] = (f32x4){0.f, 0.f, 0.f, 0.f};                                \
    _Pragma("unroll") for (int kt = 0; kt < 4; ++kt) {                      \
      const f16x8 ah = *(const f16x8*)&HIN[bq][kt * 32 + kq * 8];           \
      _Pragma("unroll") for (int i = 0; i < 4; ++i)                         \
          aH[i] = MFMA16(ah, Rh[i][kt], aH[i]);                             \
    }                                                                       \
    const float ig = sigf(aH[0][0] + zcu.x);                                \
    const float fg = sigf(aH[1][0] + zcu.y);                                \
    const float gg = tanhf_fast(aH[2][0] + zcu.z);                          \
    const float og = sigf(aH[3][0] + zcu.w);                                \
    cc = fg * cc + ig * gg;                                                 \
    hc = og * tanhf_fast(cc);                                               \
    const ushort_t hbits = f16_bits(hc);                                    \
    HOUT[kq][j] = hbits;                                                    \
    h2l[TT][kq][j] = hbits;                                                 \
    bar_lds();                                                              \
  }

    for (int tt = 0; tt < TC; tt += 2) {
      L1_STEP(hf1A, hf1B, tt);
      L1_STEP(hf1B, hf1A, tt + 1);
    }
#undef L1_STEP

    h2s[(size_t)(b0 + kq) * HDIM + j] = hc;
    c2s[(size_t)(b0 + kq) * HDIM + j] = cc;

    // ---- FC pass over the chunk (latency-tolerant, once per chunk) ----
    // last bar_lds made all h2l writes visible
    if (tid < TC * 4) {
      const int tt = tid >> 2, b = tid & 3;
      const float bfcv = bfc[0];
      float s0 = 0.f, s1 = 0.f, s2 = 0.f, s3 = 0.f;
#pragma unroll
      for (int q = 0; q < HDIM / 8; ++q) {
        const f16x8 hv = *(const f16x8*)&h2l[tt][b][q * 8];
        const float* wq = &wfl[q * 8];
        s0 += fmaxf((float)hv[0], 0.f) * wq[0];
        s1 += fmaxf((float)hv[1], 0.f) * wq[1];
        s2 += fmaxf((float)hv[2], 0.f) * wq[2];
        s3 += fmaxf((float)hv[3], 0.f) * wq[3];
        s0 += fmaxf((float)hv[4], 0.f) * wq[4];
        s1 += fmaxf((float)hv[5], 0.f) * wq[5];
        s2 += fmaxf((float)hv[6], 0.f) * wq[6];
        s3 += fmaxf((float)hv[7], 0.f) * wq[7];
      }
      const float s = s0 + s1 + s2 + s3 + bfcv;
      out[(size_t)(b0 + b) * T_SEQ + (ch - 1) * TC + tt] = fmaxf(s, 0.0f);
    }
  }
}

extern "C" void kernel_launch(void* const* d_in, const int* in_sizes, int n_in,
                              void* d_out, int out_size, void* d_ws, size_t ws_size,
                              hipStream_t stream)
{
  const float* x    = (const float*)d_in[0];
  const float* Wih0 = (const float*)d_in[1];
  const float* Whh0 = (const float*)d_in[2];
  const float* bih0 = (const float*)d_in[3];
  const float* bhh0 = (const float*)d_in[4];
  const float* Wih1 = (const float*)d_in[5];
  const float* Whh1 = (const float*)d_in[6];
  const float* bih1 = (const float*)d_in[7];
  const float* bhh1 = (const float*)d_in[8];
  const float* Wfc  = (const float*)d_in[9];
  const float* bfc  = (const float*)d_in[10];
  float* out = (float*)d_out;

  const size_t stateN = (size_t)NBATCH * HDIM;  // 65536
  float* h1s = (float*)d_ws;
  float* c1s = h1s + stateN;
  float* h2s = c1s + stateN;
  float* c2s = h2s + stateN;
  ushort_t* w0h  = (ushort_t*)(c2s + stateN);
  ushort_t* w0l  = w0h  + stateN;
  ushort_t* w1h  = w0l  + stateN;
  ushort_t* w1l  = w1h  + stateN;
  ushort_t* wi1h = w1l  + stateN;
  ushort_t* wi1l = wi1h + stateN;
  ushort_t* wxh  = wi1l + stateN;
  ushort_t* wxl  = wxh  + 512 * 32;
  ushort_t* h1buf = wxl + 512 * 32;                       // 2*NWGH*TC*4*HDIM fp16
  float* gx1buf = (float*)(h1buf + (size_t)2 * NWGH * TC * 4 * HDIM);

  // zero-init recurrent states (h0 = c0 = 0)
  (void)hipMemsetAsync(d_ws, 0, 4 * stateN * sizeof(float), stream);
  hipLaunchKernelGGL(prep_weights, dim3(256), dim3(256), 0, stream,
                     Whh0, Whh1, Wih0, Wih1,
                     w0h, w0l, w1h, w1l, wxh, wxl, wi1h, wi1l);

  for (int ch = 0; ch <= NCHUNK; ++ch) {
    hipLaunchKernelGGL(lstm_pipe, dim3(2 * NWGH), dim3(512), 0, stream,
                       x, w0h, wxh, wxl, bih0, bhh0,
                       wi1h, wi1l, w1h, bih1, bhh1, Wfc, bfc,
                       out, h1s, c1s, h2s, c2s, h1buf, gx1buf, ch);
  }
}

// Round 16
// 926.730 us; speedup vs baseline: 1.5572x; 1.0694x over previous
//
#include <hip/hip_runtime.h>

#define T_SEQ  1024
#define NBATCH 512
#define IN_DIM 16
#define HDIM   128
#define G4     (4 * HDIM)
#define TC     64
#define NCHUNK (T_SEQ / TC)
#define NWGH   128   // WGs per role; 4 batches per WG

typedef unsigned short ushort_t;
typedef __attribute__((ext_vector_type(8))) _Float16 f16x8;
typedef __attribute__((ext_vector_type(4))) float f32x4;

#define MFMA16(a, b, c) __builtin_amdgcn_mfma_f32_16x16x32_f16((a), (b), (c), 0, 0, 0)

__device__ __forceinline__ float sigf(float x) {
  return __builtin_amdgcn_rcpf(1.0f + __expf(-x));
}
__device__ __forceinline__ float tanhf_fast(float x) {
  return 1.0f - 2.0f * __builtin_amdgcn_rcpf(1.0f + __expf(2.0f * x));
}
__device__ __forceinline__ ushort_t f16_bits(float f) {
  const _Float16 h = (_Float16)f;
  return __builtin_bit_cast(unsigned short, h);
}
__device__ __forceinline__ void split_f16(float f, ushort_t* hi, ushort_t* lo) {
  const _Float16 h = (_Float16)f;
  *hi = __builtin_bit_cast(unsigned short, h);
  const _Float16 l = (_Float16)(f - (float)h);
  *lo = __builtin_bit_cast(unsigned short, l);
}
// barrier that waits only on LDS ops (global stores stay in flight)
__device__ __forceinline__ void bar_lds() {
  asm volatile("s_waitcnt lgkmcnt(0)\n\ts_barrier" ::: "memory");
}

// ---------------- prep: split weights into fp16 hi/lo ----------------
__global__ __launch_bounds__(256) void prep_weights(
    const float* __restrict__ Whh0, const float* __restrict__ Whh1,
    const float* __restrict__ Wih0, const float* __restrict__ Wih1,
    ushort_t* __restrict__ w0h, ushort_t* __restrict__ w0l,
    ushort_t* __restrict__ w1h, ushort_t* __restrict__ w1l,
    ushort_t* __restrict__ wxh, ushort_t* __restrict__ wxl,
    ushort_t* __restrict__ wi1h, ushort_t* __restrict__ wi1l)
{
  const int idx = blockIdx.x * 256 + threadIdx.x;
  if (idx < 512 * HDIM) {
    split_f16(Whh0[idx], &w0h[idx], &w0l[idx]);
    split_f16(Whh1[idx], &w1h[idx], &w1l[idx]);
    split_f16(Wih1[idx], &wi1h[idx], &wi1l[idx]);
  }
  if (idx < 512 * 32) {  // Wih0 zero-padded K=16 -> 32
    const int g = idx >> 5, k = idx & 31;
    const float f = (k < IN_DIM) ? Wih0[g * IN_DIM + k] : 0.0f;
    split_f16(f, &wxh[idx], &wxl[idx]);
  }
}

// LDS overlay (union of the two roles' pools)
struct L0LDS {
  __align__(16) ushort_t hfA[4][144];
  __align__(16) ushort_t hfB[4][144];
  __align__(16) ushort_t xlds[4][TC][32];
  __align__(16) float gx0s[8 * 4 * 128 * 4];  // [t_local][b][j][gate], 64 KB
};
struct L1LDS {
  __align__(16) ushort_t hfA[4][144];
  __align__(16) ushort_t hfB[4][144];
  __align__(16) ushort_t h2l[TC][4][136];
  __align__(16) float wfl[HDIM];
};

// ---------------- pipelined launch: l0(ch) on WGs [0,128), gemm+l1(ch-1) on
// WGs [128,256). Gate cols permuted (g = i*128 + wv*16 + row); A rows carry
// batch = row>>2 -> in-lane update on all 64 lanes. Recurrent h.Whh uses fp16
// HI only (validated R14/R15). NEW: L0's x-contribution is hoisted into a
// per-8-step sub-chunk GEMM (x.Wih0^T + bias -> LDS gx0s), making the L0 step
// loop 16 MFMAs + LDS zc read — same structure as L1. L1's gx1 GEMM drops the
// W_lo term (same error structure as the validated recurrent-W_lo drop).
__global__ __launch_bounds__(512, 2) void lstm_pipe(
    const float* __restrict__ x,
    const ushort_t* __restrict__ w0h,
    const ushort_t* __restrict__ wxh, const ushort_t* __restrict__ wxl,
    const float* __restrict__ bih0, const float* __restrict__ bhh0,
    const ushort_t* __restrict__ wi1h,
    const ushort_t* __restrict__ w1h,
    const float* __restrict__ bih1, const float* __restrict__ bhh1,
    const float* __restrict__ Wfc, const float* __restrict__ bfc,
    float* __restrict__ out,
    float* __restrict__ h1s, float* __restrict__ c1s,
    float* __restrict__ h2s, float* __restrict__ c2s,
    ushort_t* __restrict__ h1buf,   // [2][NWGH][TC*4][HDIM] fp16
    float* __restrict__ gx1buf,     // [NWGH][TC*4][HDIM][4]
    int ch)
{
  const int tid  = threadIdx.x;
  const int lane = tid & 63;
  const int wv   = tid >> 6;
  const int row  = lane & 15;
  const int kq   = lane >> 4;    // = this lane's batch in the update phase
  const int bq   = row >> 2;     // A-fragment batch for this lane's A row
  const int j    = wv * 16 + row;

  constexpr size_t POOL =
      sizeof(L0LDS) > sizeof(L1LDS) ? sizeof(L0LDS) : sizeof(L1LDS);
  __shared__ __align__(16) char pool[POOL];

  if (blockIdx.x < NWGH) {
    // ================= L0 ROLE: chunk ch =================
    if (ch >= NCHUNK) return;
    L0LDS& S = *(L0LDS*)pool;
    const int w  = blockIdx.x;
    const int b0 = w * 4;

    f16x8 Bh[4][4], Bxh[4], Bxl[4];
#pragma unroll
    for (int i = 0; i < 4; ++i) {
      const int g = i * 128 + j;
#pragma unroll
      for (int kt = 0; kt < 4; ++kt)
        Bh[i][kt] = *(const f16x8*)&w0h[g * HDIM + kt * 32 + kq * 8];
      Bxh[i] = *(const f16x8*)&wxh[g * 32 + kq * 8];
      Bxl[i] = *(const f16x8*)&wxl[g * 32 + kq * 8];
    }

    // stage this chunk's x as fp16 (2 threads per (b,ts) row)
    {
      const int r = tid >> 1, half = tid & 1;
      const int b = r >> 6, ts = r & (TC - 1);
      const float* src =
          &x[((size_t)(b0 + b) * T_SEQ + ch * TC + ts) * IN_DIM + half * 8];
      const float4 v0 = *(const float4*)&src[0];
      const float4 v1 = *(const float4*)&src[4];
      ushort_t* dst = &S.xlds[b][ts][half * 8];
      dst[0] = f16_bits(v0.x); dst[1] = f16_bits(v0.y);
      dst[2] = f16_bits(v0.z); dst[3] = f16_bits(v0.w);
      dst[4] = f16_bits(v1.x); dst[5] = f16_bits(v1.y);
      dst[6] = f16_bits(v1.z); dst[7] = f16_bits(v1.w);
      *(float4*)&S.xlds[b][ts][16 + half * 8] = (float4){0.f, 0.f, 0.f, 0.f};
    }

    float bz[4];
#pragma unroll
    for (int i = 0; i < 4; ++i) bz[i] = bih0[i * 128 + j] + bhh0[i * 128 + j];
    float hc = h1s[(size_t)(b0 + kq) * HDIM + j];
    float cc = c1s[(size_t)(b0 + kq) * HDIM + j];
    S.hfA[kq][j] = f16_bits(hc);
    __syncthreads();

    ushort_t* hbp = h1buf + ((size_t)(ch & 1) * NWGH + w) * (TC * 4 * HDIM) +
                    (size_t)kq * HDIM + j;

#define L0_STEP(HIN, HOUT, TT)                                              \
  {                                                                         \
    const float4 zcu =                                                      \
        *(const float4*)&S.gx0s[((((TT) & 7) * 4 + kq) * 128 + j) * 4];     \
    f32x4 aH[4];                                                            \
    _Pragma("unroll") for (int i = 0; i < 4; ++i)                           \
        aH[i] = (f32x4){0.f, 0.f, 0.f, 0.f};                                \
    _Pragma("unroll") for (int kt = 0; kt < 4; ++kt) {                      \
      const f16x8 ah = *(const f16x8*)&S.HIN[bq][kt * 32 + kq * 8];         \
      _Pragma("unroll") for (int i = 0; i < 4; ++i)                         \
          aH[i] = MFMA16(ah, Bh[i][kt], aH[i]);                             \
    }                                                                       \
    const float ig = sigf(aH[0][0] + zcu.x);                                \
    const float fg = sigf(aH[1][0] + zcu.y);                                \
    const float gg = tanhf_fast(aH[2][0] + zcu.z);                          \
    const float og = sigf(aH[3][0] + zcu.w);                                \
    cc = fg * cc + ig * gg;                                                 \
    hc = og * tanhf_fast(cc);                                               \
    const ushort_t hbits = f16_bits(hc);                                    \
    S.HOUT[kq][j] = hbits;                                                  \
    *hbp = hbits;                                                           \
    hbp += 4 * HDIM;                                                        \
    bar_lds();                                                              \
  }

    for (int sc = 0; sc < TC / 8; ++sc) {
      // ---- sub-chunk GEMM: gx0 = x . Wih0^T + bias for 8 steps -> LDS ----
      // (prev sub-chunk's reads finished at its last step's barrier)
#pragma unroll
      for (int mt = 0; mt < 2; ++mt) {
        const f16x8 a =
            *(const f16x8*)&S.xlds[row & 3][sc * 8 + mt * 4 + (row >> 2)][kq * 8];
        f32x4 acc[4];
#pragma unroll
        for (int i = 0; i < 4; ++i) acc[i] = (f32x4){0.f, 0.f, 0.f, 0.f};
#pragma unroll
        for (int i = 0; i < 4; ++i) acc[i] = MFMA16(a, Bxh[i], acc[i]);
#pragma unroll
        for (int i = 0; i < 4; ++i) acc[i] = MFMA16(a, Bxl[i], acc[i]);
#pragma unroll
        for (int r = 0; r < 4; ++r) {
          // C row = kq*4+r -> t_local = mt*4+kq, batch = r
          float4 o;
          o.x = acc[0][r] + bz[0];
          o.y = acc[1][r] + bz[1];
          o.z = acc[2][r] + bz[2];
          o.w = acc[3][r] + bz[3];
          *(float4*)&S.gx0s[(((mt * 4 + kq) * 4 + r) * 128 + j) * 4] = o;
        }
      }
      bar_lds();
      // ---- 8 recurrent steps ----
#pragma unroll 1
      for (int q = 0; q < 4; ++q) {
        const int tt = sc * 8 + q * 2;
        L0_STEP(hfA, hfB, tt);
        L0_STEP(hfB, hfA, tt + 1);
      }
    }
#undef L0_STEP

    h1s[(size_t)(b0 + kq) * HDIM + j] = hc;
    c1s[(size_t)(b0 + kq) * HDIM + j] = cc;
  } else {
    // ================= L1 ROLE: gemm + recurrence, FC at chunk end =========
    if (ch == 0) return;
    L1LDS& S = *(L1LDS*)pool;
    const int w  = blockIdx.x - NWGH;
    const int b0 = w * 4;

    const ushort_t* hb =
        h1buf + ((size_t)((ch - 1) & 1) * NWGH + w) * (TC * 4 * HDIM);
    float* gx = gx1buf + (size_t)w * (TC * 4 * HDIM * 4);

    if (tid < HDIM) S.wfl[tid] = Wfc[tid];

    // ---- gemm: gx1 = h1 . Wih1^T + biases (hi only), own 4 batches ----
    {
      f16x8 Gh[4][4];
      float bz1[4];
#pragma unroll
      for (int i = 0; i < 4; ++i) {
        const int g = i * 128 + j;
#pragma unroll
        for (int kt = 0; kt < 4; ++kt)
          Gh[i][kt] = *(const f16x8*)&wi1h[g * HDIM + kt * 32 + kq * 8];
        bz1[i] = bih1[i * 128 + j] + bhh1[i * 128 + j];
      }
#pragma unroll 2
      for (int mt = 0; mt < TC * 4 / 16; ++mt) {
        f32x4 acc[4];
#pragma unroll
        for (int i = 0; i < 4; ++i) acc[i] = (f32x4){0.f, 0.f, 0.f, 0.f};
#pragma unroll
        for (int kt = 0; kt < 4; ++kt) {
          const f16x8 a =
              *(const f16x8*)&hb[(size_t)(mt * 16 + row) * HDIM + kt * 32 + kq * 8];
#pragma unroll
          for (int i = 0; i < 4; ++i) acc[i] = MFMA16(a, Gh[i][kt], acc[i]);
        }
#pragma unroll
        for (int r = 0; r < 4; ++r) {
          const int m = mt * 16 + kq * 4 + r;
          float4 o;
          o.x = acc[0][r] + bz1[0];
          o.y = acc[1][r] + bz1[1];
          o.z = acc[2][r] + bz1[2];
          o.w = acc[3][r] + bz1[3];
          *(float4*)&gx[((size_t)m * HDIM + j) * 4] = o;
        }
      }
    }

    float hc = h2s[(size_t)(b0 + kq) * HDIM + j];
    float cc = c2s[(size_t)(b0 + kq) * HDIM + j];
    S.hfA[kq][j] = f16_bits(hc);
    __syncthreads();  // drains gemm stores (vmcnt) + hfA/wfl staging

    f16x8 Rh[4][4];
#pragma unroll
    for (int i = 0; i < 4; ++i) {
      const int g = i * 128 + j;
#pragma unroll
      for (int kt = 0; kt < 4; ++kt)
        Rh[i][kt] = *(const f16x8*)&w1h[g * HDIM + kt * 32 + kq * 8];
    }

    // per-step stride: 4 rows x HDIM x 4 floats = 2048 floats = 512 float4
    const float4* gxp = (const float4*)&gx[((size_t)kq * HDIM + j) * 4];
    float4 zcc = *gxp;
    gxp += 512;

#define L1_STEP(HIN, HOUT, TT)                                              \
  {                                                                         \
    const float4 zcu = zcc;                                                 \
    if ((TT) + 1 < TC) { zcc = *gxp; gxp += 512; }                          \
    f32x4 aH[4];                                                            \
    _Pragma("unroll") for (int i = 0; i < 4; ++i)                           \
        aH[i] = (f32x4){0.f, 0.f, 0.f, 0.f};                                \
    _Pragma("unroll") for (int kt = 0; kt < 4; ++kt) {                      \
      const f16x8 ah = *(const f16x8*)&S.HIN[bq][kt * 32 + kq * 8];         \
      _Pragma("unroll") for (int i = 0; i < 4; ++i)                         \
          aH[i] = MFMA16(ah, Rh[i][kt], aH[i]);                             \
    }                                                                       \
    const float ig = sigf(aH[0][0] + zcu.x);                                \
    const float fg = sigf(aH[1][0] + zcu.y);                                \
    const float gg = tanhf_fast(aH[2][0] + zcu.z);                          \
    const float og = sigf(aH[3][0] + zcu.w);                                \
    cc = fg * cc + ig * gg;                                                 \
    hc = og * tanhf_fast(cc);                                               \
    const ushort_t hbits = f16_bits(hc);                                    \
    S.HOUT[kq][j] = hbits;                                                  \
    S.h2l[TT][kq][j] = hbits;                                               \
    bar_lds();                                                              \
  }

    for (int tt = 0; tt < TC; tt += 2) {
      L1_STEP(hfA, hfB, tt);
      L1_STEP(hfB, hfA, tt + 1);
    }
#undef L1_STEP

    h2s[(size_t)(b0 + kq) * HDIM + j] = hc;
    c2s[(size_t)(b0 + kq) * HDIM + j] = cc;

    // ---- FC pass over the chunk (latency-tolerant, once per chunk) ----
    // last bar_lds made all h2l writes visible
    if (tid < TC * 4) {
      const int tt = tid >> 2, b = tid & 3;
      const float bfcv = bfc[0];
      float s0 = 0.f, s1 = 0.f, s2 = 0.f, s3 = 0.f;
#pragma unroll
      for (int q = 0; q < HDIM / 8; ++q) {
        const f16x8 hv = *(const f16x8*)&S.h2l[tt][b][q * 8];
        const float* wq = &S.wfl[q * 8];
        s0 += fmaxf((float)hv[0], 0.f) * wq[0];
        s1 += fmaxf((float)hv[1], 0.f) * wq[1];
        s2 += fmaxf((float)hv[2], 0.f) * wq[2];
        s3 += fmaxf((float)hv[3], 0.f) * wq[3];
        s0 += fmaxf((float)hv[4], 0.f) * wq[4];
        s1 += fmaxf((float)hv[5], 0.f) * wq[5];
        s2 += fmaxf((float)hv[6], 0.f) * wq[6];
        s3 += fmaxf((float)hv[7], 0.f) * wq[7];
      }
      const float s = s0 + s1 + s2 + s3 + bfcv;
      out[(size_t)(b0 + b) * T_SEQ + (ch - 1) * TC + tt] = fmaxf(s, 0.0f);
    }
  }
}

extern "C" void kernel_launch(void* const* d_in, const int* in_sizes, int n_in,
                              void* d_out, int out_size, void* d_ws, size_t ws_size,
                              hipStream_t stream)
{
  const float* x    = (const float*)d_in[0];
  const float* Wih0 = (const float*)d_in[1];
  const float* Whh0 = (const float*)d_in[2];
  const float* bih0 = (const float*)d_in[3];
  const float* bhh0 = (const float*)d_in[4];
  const float* Wih1 = (const float*)d_in[5];
  const float* Whh1 = (const float*)d_in[6];
  const float* bih1 = (const float*)d_in[7];
  const float* bhh1 = (const float*)d_in[8];
  const float* Wfc  = (const float*)d_in[9];
  const float* bfc  = (const float*)d_in[10];
  float* out = (float*)d_out;

  const size_t stateN = (size_t)NBATCH * HDIM;  // 65536
  float* h1s = (float*)d_ws;
  float* c1s = h1s + stateN;
  float* h2s = c1s + stateN;
  float* c2s = h2s + stateN;
  ushort_t* w0h  = (ushort_t*)(c2s + stateN);
  ushort_t* w0l  = w0h  + stateN;
  ushort_t* w1h  = w0l  + stateN;
  ushort_t* w1l  = w1h  + stateN;
  ushort_t* wi1h = w1l  + stateN;
  ushort_t* wi1l = wi1h + stateN;
  ushort_t* wxh  = wi1l + stateN;
  ushort_t* wxl  = wxh  + 512 * 32;
  ushort_t* h1buf = wxl + 512 * 32;                       // 2*NWGH*TC*4*HDIM fp16
  float* gx1buf = (float*)(h1buf + (size_t)2 * NWGH * TC * 4 * HDIM);

  // zero-init recurrent states (h0 = c0 = 0)
  (void)hipMemsetAsync(d_ws, 0, 4 * stateN * sizeof(float), stream);
  hipLaunchKernelGGL(prep_weights, dim3(256), dim3(256), 0, stream,
                     Whh0, Whh1, Wih0, Wih1,
                     w0h, w0l, w1h, w1l, wxh, wxl, wi1h, wi1l);

  for (int ch = 0; ch <= NCHUNK; ++ch) {
    hipLaunchKernelGGL(lstm_pipe, dim3(2 * NWGH), dim3(512), 0, stream,
                       x, w0h, wxh, wxl, bih0, bhh0,
                       wi1h, w1h, bih1, bhh1, Wfc, bfc,
                       out, h1s, c1s, h2s, c2s, h1buf, gx1buf, ch);
  }
}